// Round 2
// baseline (175.149 us; speedup 1.0000x reference)
//
#include <hip/hip_runtime.h>
#include <math.h>

#define Bb 4
#define Cc 256
#define Nn 4096
#define Dd 32
#define XST 264   // proj x-tile LDS row stride (shorts)

typedef __attribute__((ext_vector_type(8))) short bf16x8;
typedef __attribute__((ext_vector_type(4))) float f32x4;

__device__ __forceinline__ unsigned short f2bf(float x) {
    union { float f; unsigned u; } c; c.f = x;
    unsigned r = c.u + 0x7fffu + ((c.u >> 16) & 1u);   // RNE
    return (unsigned short)(r >> 16);
}
__device__ __forceinline__ unsigned pk2(float a, float b) {
    return (unsigned)f2bf(a) | ((unsigned)f2bf(b) << 16);
}
__device__ __forceinline__ void load_lds16(const void* g, void* l) {
    __builtin_amdgcn_global_load_lds(
        (const __attribute__((address_space(1))) void*)g,
        (__attribute__((address_space(3))) void*)l, 16, 0, 0);
}
__device__ __forceinline__ float fexp2(float x) {
#if __has_builtin(__builtin_amdgcn_exp2f)
    return __builtin_amdgcn_exp2f(x);
#else
    return __exp2f(x);
#endif
}
// DPP sum over the 16-lane row (used ONCE, after the jt loop)
template <int CTRL>
__device__ __forceinline__ float dppf(float v) {
    int iv = __builtin_bit_cast(int, v);
    return __builtin_bit_cast(float,
        __builtin_amdgcn_update_dpp(iv, iv, CTRL, 0xF, 0xF, false));
}
__device__ __forceinline__ float rowsum16(float v) {
    v += dppf<0xB1>(v);    // quad xor1
    v += dppf<0x4E>(v);    // quad xor2
    v += dppf<0x141>(v);   // row_half_mirror
    v += dppf<0x140>(v);   // row_mirror
    return v;
}

// ---------------------------------------------------------------------------
// pack_w: W (q|k|v concat, 320 rows x 256) -> bf16 MFMA-fragment-major layout.
// wpk index: (((ot*8 + kc)*16 + m)*4 + qd) * 8 shorts = lane (qd,m)'s 16B frag
// for o = 16*ot+m, c = 32*kc+8*qd.. . Q rows pre-scaled by log2(e) so attn's
// softmax is a bare exp2. grid 40 x 256.   (UNCHANGED)
// ---------------------------------------------------------------------------
__global__ __launch_bounds__(256) void pack_w(
    const float* __restrict__ qw, const float* __restrict__ kw,
    const float* __restrict__ vw, short* __restrict__ wpk) {
    const int g = blockIdx.x * 256 + threadIdx.x;   // 10240 frags
    const int qd = g & 3, m = (g >> 2) & 15, kc = (g >> 6) & 7, ot = g >> 9;
    const int o = 16 * ot + m;
    const float* src;
    float scale = 1.0f;
    if (o < 32)      { src = qw + (size_t)o * Cc; scale = 1.44269504088896f; }
    else if (o < 64) { src = kw + (size_t)(o - 32) * Cc; }
    else             { src = vw + (size_t)(o - 64) * Cc; }
    const float* s8 = src + 32 * kc + 8 * qd;
    uint4 u;
    u.x = pk2(s8[0] * scale, s8[1] * scale);
    u.y = pk2(s8[2] * scale, s8[3] * scale);
    u.z = pk2(s8[4] * scale, s8[5] * scale);
    u.w = pk2(s8[6] * scale, s8[7] * scale);
    *(uint4*)(wpk + (size_t)g * 8) = u;
}

// ---------------------------------------------------------------------------
// proj: qkv = W x, bf16 MFMA, A-frags streamed from packed W (coalesced 16B).
// grid (Nn/32, 1, B) = 512 blocks, 256 thr.  x^T staged in LDS (32n x 256c).
// Outputs: q_t/k_t [b][n][32d]; v_b [b][c][n~] kappa-permuted within 64-groups
// (slot(j) = 4*(j&15) + (j>>4)) to match attn's packed P writes.  (UNCHANGED)
// ---------------------------------------------------------------------------
__global__ __launch_bounds__(256) void proj(
    const float* __restrict__ x, const short* __restrict__ wpk,
    short* __restrict__ q_t, short* __restrict__ k_t, short* __restrict__ v_b) {
    __shared__ alignas(16) short xs[32 * XST];   // 16.9 KB
    const int b = blockIdx.z;
    const int n0 = blockIdx.x * 32;
    const int tid = threadIdx.x;
    const int w = tid >> 6;
    const int lane = tid & 63, qd = lane >> 4, m = lane & 15;

    // ---- stage x^T tile (bf16): thread t covers n = t&31, c-range 32*(t>>5) ----
    {
        const int n = tid & 31, cg = tid >> 5;
        const float* xp = x + ((size_t)b * Cc + 32 * cg) * Nn + n0 + n;
        float xv[32];
#pragma unroll
        for (int i = 0; i < 32; ++i) xv[i] = xp[(size_t)i * Nn];
        short* row = xs + n * XST + 32 * cg;
#pragma unroll
        for (int u4 = 0; u4 < 4; ++u4)
            *(uint4*)(row + 8 * u4) = make_uint4(
                pk2(xv[8*u4+0], xv[8*u4+1]), pk2(xv[8*u4+2], xv[8*u4+3]),
                pk2(xv[8*u4+4], xv[8*u4+5]), pk2(xv[8*u4+6], xv[8*u4+7]));
    }
    __syncthreads();

    // ---- GEMM: wave w owns o-tiles ot = 4i + w ----
    const int fslot = m * 4 + qd;
    f32x4 acc[5][2];
#pragma unroll
    for (int i = 0; i < 5; ++i)
#pragma unroll
        for (int nt = 0; nt < 2; ++nt) acc[i][nt] = (f32x4){0.f, 0.f, 0.f, 0.f};

    bf16x8 afc[5], afn[5];
#pragma unroll
    for (int i = 0; i < 5; ++i)
        afc[i] = *(const bf16x8*)(wpk + ((size_t)((4*i + w) * 8 + 0) * 64 + fslot) * 8);

    for (int kc = 0; kc < 8; ++kc) {
        if (kc < 7) {
#pragma unroll
            for (int i = 0; i < 5; ++i)
                afn[i] = *(const bf16x8*)(
                    wpk + ((size_t)((4*i + w) * 8 + kc + 1) * 64 + fslot) * 8);
        }
        const bf16x8 b0 = *(const bf16x8*)&xs[(     m) * XST + 32 * kc + 8 * qd];
        const bf16x8 b1 = *(const bf16x8*)&xs[(16 + m) * XST + 32 * kc + 8 * qd];
#pragma unroll
        for (int i = 0; i < 5; ++i)
            acc[i][0] = __builtin_amdgcn_mfma_f32_16x16x32_bf16(afc[i], b0, acc[i][0], 0, 0, 0);
#pragma unroll
        for (int i = 0; i < 5; ++i)
            acc[i][1] = __builtin_amdgcn_mfma_f32_16x16x32_bf16(afc[i], b1, acc[i][1], 0, 0, 0);
#pragma unroll
        for (int i = 0; i < 5; ++i) afc[i] = afn[i];
    }

    // ---- epilogue: C row = 16*ot + 4*qd + rr, col n = n0 + 16*nt + m ----
#pragma unroll
    for (int i = 0; i < 5; ++i) {
        const int ot = 4 * i + w;
        if (ot < 4) {
            short* dst = (ot < 2 ? q_t : k_t) + (size_t)b * Nn * Dd;
            const int dbase = (ot & 1) * 16 + 4 * qd;
#pragma unroll
            for (int nt = 0; nt < 2; ++nt) {
                const f32x4 a = acc[i][nt];
                *(uint2*)(dst + (size_t)(n0 + 16 * nt + m) * Dd + dbase) =
                    make_uint2(pk2(a[0], a[1]), pk2(a[2], a[3]));
            }
        } else {
            const int cbase = (ot - 4) * 16 + 4 * qd;
            const int gbase = n0 & ~63;
            const int off2 = (n0 & 32) ? 2 : 0;
#pragma unroll
            for (int rr = 0; rr < 4; ++rr) {
                const unsigned pv = pk2(acc[i][0][rr], acc[i][1][rr]);
                *(unsigned*)(v_b + ((size_t)b * Cc + cbase + rr) * Nn +
                             gbase + 4 * m + off2) = pv;
            }
        }
    }
}

// ---------------------------------------------------------------------------
// attn: flash attention, 64 q-rows x ALL 256 channels per block (softmax
// dedup). grid (Nn/64, 1, B) = 256 blocks, 512 threads.
//   QK/softmax: wave (rt=w&3, kh=w>>2): rows 16rt.., keys 32kh.. (2 MFMA,
//     8 exp2, pk2-RNE packs). P -> LDS, kappa = 4m+nt (proj-compatible).
//   PV: wave w owns channels 32w..32w+31; V fragments read DIRECTLY from
//     global (kappa-packed v_b granule == MFMA B-frag; no LDS round-trip).
//   K double-buffered in LDS; prefetch issued AFTER B2 so it stays in
//     flight through PV and drains at the next B1 (proven round-0 pattern).
//   l split per kh-half, summed in epilogue.  LDS 34.3 KB.
// Bisection round: no setprio, no XCD decode, no cvt_pk asm.
// ---------------------------------------------------------------------------
__global__ __launch_bounds__(512) void attn(
    const float* __restrict__ x, const short* __restrict__ q_t,
    const short* __restrict__ k_t, const short* __restrict__ v_b,
    const float* __restrict__ gamma, float* __restrict__ out) {
    __shared__ alignas(16) char pool[34304];
    short* q_s = (short*)pool;                    // [64][32] bf16, 4 KB (loop)
    short* p_s = (short*)(pool + 12288);          // [64][72] bf16, 9.2 KB (loop)
    float* o_t = (float*)pool;                    // [64][132] f32 epilogue overlay
    float* l_s = (float*)(pool + 33792);          // [2][64] f32

    const int b  = blockIdx.z;
    const int i0 = blockIdx.x * 64;
    const int tid = threadIdx.x;
    const int w = tid >> 6, lane = tid & 63;
    const int qd = lane >> 4, m = lane & 15;
    const int rt = w & 3, kh = w >> 2;

    const short* ktb = k_t + (size_t)b * Nn * Dd;
    // per-lane V base: channel 32w+m (+16ct later), kappa granule 8qd
    const short* vpb = v_b + ((size_t)(b * Cc) + 32 * w + m) * Nn + 8 * qd;

    // stage Q (waves 0-3) + first K tile (waves 4-7)
    if (tid < 256) {
        load_lds16(q_t + ((size_t)b * Nn + i0) * Dd + tid * 8, q_s + tid * 8);
    } else {
        load_lds16(ktb + (size_t)(tid - 256) * 8,
                   (short*)(pool + 4096) + (tid - 256) * 8);
    }
    __syncthreads();   // vmcnt drained at barrier

    // loop-invariant Q fragment (rows 16rt..16rt+15)
    const bf16x8 af = *(const bf16x8*)(q_s + (16 * rt + m) * Dd + 8 * qd);

    f32x4 oacc[4][2];
#pragma unroll
    for (int mt = 0; mt < 4; ++mt)
#pragma unroll
        for (int ct = 0; ct < 2; ++ct) oacc[mt][ct] = (f32x4){0.f, 0.f, 0.f, 0.f};
    float l_i[4] = {0.f, 0.f, 0.f, 0.f};

    int cur = 0;
    for (int jt = 0; jt < Nn / 64; ++jt) {
        const int j0 = jt * 64;
        const short* k_s = (const short*)(pool + 4096 + 4096 * cur);
        if (jt) __syncthreads();   // B1: K[cur] + prior prefetch arrived

        // V fragments for THIS tile, straight from global (L2-hit).
        bf16x8 vf[2][2];
#pragma unroll
        for (int ct = 0; ct < 2; ++ct)
#pragma unroll
            for (int kc = 0; kc < 2; ++kc)
                vf[ct][kc] = *(const bf16x8*)(
                    vpb + (size_t)(16 * ct) * Nn + j0 + 32 * kc);

        // ---- S' = (log2e*Q) K^T : 16 rows x 32 keys per wave ----
        const bf16x8 bk0 = *(const bf16x8*)(k_s + (16 * (2 * kh + 0) + m) * Dd + 8 * qd);
        const bf16x8 bk1 = *(const bf16x8*)(k_s + (16 * (2 * kh + 1) + m) * Dd + 8 * qd);
        const f32x4 s0 = __builtin_amdgcn_mfma_f32_16x16x32_bf16(
            af, bk0, (f32x4){0.f, 0.f, 0.f, 0.f}, 0, 0, 0);
        const f32x4 s1 = __builtin_amdgcn_mfma_f32_16x16x32_bf16(
            af, bk1, (f32x4){0.f, 0.f, 0.f, 0.f}, 0, 0, 0);

        // ---- P = exp2(S'), l partials, packed kappa P write ----
        // kappa(j=16nt+m) = 4m+nt: pair (nt=2kh, 2kh+1) -> u32 @ [row][4m+2kh]
#pragma unroll
        for (int rr = 0; rr < 4; ++rr) {
            const float p0 = fexp2(s0[rr]);
            const float p1 = fexp2(s1[rr]);
            l_i[rr] += p0 + p1;
            *(unsigned*)&p_s[(16 * rt + 4 * qd + rr) * 72 + 4 * m + 2 * kh] =
                pk2(p0, p1);
        }
        __syncthreads();   // B2: p_s visible

        // K prefetch for next tile (waves 4-7) — stays in flight through PV
        if (jt + 1 < Nn / 64 && tid >= 256)
            load_lds16(ktb + (size_t)(j0 + 64) * Dd + (tid - 256) * 8,
                       (short*)(pool + 4096 + 4096 * (cur ^ 1)) + (tid - 256) * 8);

        // ---- PV: O[64 x 32 ch] += P V^T, V frags from registers ----
#pragma unroll
        for (int kc = 0; kc < 2; ++kc) {
            bf16x8 pa[4];
#pragma unroll
            for (int mt = 0; mt < 4; ++mt)
                pa[mt] = *(const bf16x8*)&p_s[(16 * mt + m) * 72 + 32 * kc + 8 * qd];
#pragma unroll
            for (int ct = 0; ct < 2; ++ct)
#pragma unroll
                for (int mt = 0; mt < 4; ++mt)
                    oacc[mt][ct] = __builtin_amdgcn_mfma_f32_16x16x32_bf16(
                        pa[mt], vf[ct][kc], oacc[mt][ct], 0, 0, 0);
        }
        cur ^= 1;
    }

    // final l reduction: per kh-half row sums, combined in epilogue
#pragma unroll
    for (int rr = 0; rr < 4; ++rr) l_i[rr] = rowsum16(l_i[rr]);
    if (m == 0)
        *(f32x4*)&l_s[kh * 64 + 16 * rt + 4 * qd] =
            (f32x4){l_i[0], l_i[1], l_i[2], l_i[3]};
    __syncthreads();   // l published; loop LDS dead -> o_t overlay safe

    // ---- epilogue: transpose O via LDS overlay, out = gamma*O/l + x ----
    const float g = gamma[0];
    const int i = lane;
    const float linv = 1.0f / (l_s[i] + l_s[64 + i]);
#pragma unroll
    for (int ps = 0; ps < 2; ++ps) {
        if (ps) __syncthreads();
#pragma unroll
        for (int mt = 0; mt < 4; ++mt)
#pragma unroll
            for (int rr = 0; rr < 4; ++rr)
                o_t[(16 * mt + 4 * qd + rr) * 132 + 16 * w + m] = oacc[mt][ps][rr];
        __syncthreads();
#pragma unroll
        for (int u = 0; u < 4; ++u) {
            const f32x4 v4 = *(const f32x4*)&o_t[i * 132 + 16 * w + 4 * u];
#pragma unroll
            for (int e = 0; e < 4; ++e) {
                const int c = 32 * w + 16 * ps + 4 * u + e;
                const size_t gidx = ((size_t)b * Cc + c) * Nn + i0 + i;
                out[gidx] = g * v4[e] * linv + x[gidx];
            }
        }
    }
}

// ---------------------------------------------------------------------------
extern "C" void kernel_launch(void* const* d_in, const int* in_sizes, int n_in,
                              void* d_out, int out_size, void* d_ws, size_t ws_size,
                              hipStream_t stream) {
    const float* x     = (const float*)d_in[0];
    const float* qw    = (const float*)d_in[1];
    const float* kw    = (const float*)d_in[2];
    const float* vw    = (const float*)d_in[3];
    const float* gamma = (const float*)d_in[4];
    float* out = (float*)d_out;

    short* q_t = (short*)d_ws;                       // [b][n][32] bf16, 1 MB
    short* k_t = q_t + (size_t)Bb * Nn * Dd;         // [b][n][32] bf16, 1 MB
    short* v_b = k_t + (size_t)Bb * Nn * Dd;         // [b][c][n~] bf16, 8.4 MB
    short* wpk = v_b + (size_t)Bb * Cc * Nn;         // 160 KB packed W

    pack_w<<<dim3(40), 256, 0, stream>>>(qw, kw, vw, wpk);
    proj<<<dim3(Nn / 32, 1, Bb), 256, 0, stream>>>(x, wpk, q_t, k_t, v_b);
    attn<<<dim3(Nn / 64, 1, Bb), 512, 0, stream>>>(x, q_t, k_t, v_b, gamma, out);
}

// Round 3
// 150.062 us; speedup vs baseline: 1.1672x; 1.1672x over previous
//
#include <hip/hip_runtime.h>
#include <math.h>

#define Bb 4
#define Cc 256
#define Nn 4096
#define Dd 32
#define XST 264   // proj x-tile LDS row stride (shorts)

typedef __attribute__((ext_vector_type(8))) short bf16x8;
typedef __attribute__((ext_vector_type(4))) float f32x4;

__device__ __forceinline__ unsigned short f2bf(float x) {
    union { float f; unsigned u; } c; c.f = x;
    unsigned r = c.u + 0x7fffu + ((c.u >> 16) & 1u);   // RNE
    return (unsigned short)(r >> 16);
}
__device__ __forceinline__ unsigned pk2(float a, float b) {
    return (unsigned)f2bf(a) | ((unsigned)f2bf(b) << 16);
}
__device__ __forceinline__ void load_lds16(const void* g, void* l) {
    __builtin_amdgcn_global_load_lds(
        (const __attribute__((address_space(1))) void*)g,
        (__attribute__((address_space(3))) void*)l, 16, 0, 0);
}
__device__ __forceinline__ float fexp2(float x) {
#if __has_builtin(__builtin_amdgcn_exp2f)
    return __builtin_amdgcn_exp2f(x);
#else
    return __exp2f(x);
#endif
}
// DPP sum over the 16-lane row (used ONCE, after the jt loop)
template <int CTRL>
__device__ __forceinline__ float dppf(float v) {
    int iv = __builtin_bit_cast(int, v);
    return __builtin_bit_cast(float,
        __builtin_amdgcn_update_dpp(iv, iv, CTRL, 0xF, 0xF, false));
}
__device__ __forceinline__ float rowsum16(float v) {
    v += dppf<0xB1>(v);    // quad xor1
    v += dppf<0x4E>(v);    // quad xor2
    v += dppf<0x141>(v);   // row_half_mirror
    v += dppf<0x140>(v);   // row_mirror
    return v;
}

// ---------------------------------------------------------------------------
// pack_w: W (q|k|v concat, 320 rows x 256) -> bf16 MFMA-fragment-major layout.
// Q rows pre-scaled by log2(e). grid 40 x 256.   (UNCHANGED)
// ---------------------------------------------------------------------------
__global__ __launch_bounds__(256) void pack_w(
    const float* __restrict__ qw, const float* __restrict__ kw,
    const float* __restrict__ vw, short* __restrict__ wpk) {
    const int g = blockIdx.x * 256 + threadIdx.x;   // 10240 frags
    const int qd = g & 3, m = (g >> 2) & 15, kc = (g >> 6) & 7, ot = g >> 9;
    const int o = 16 * ot + m;
    const float* src;
    float scale = 1.0f;
    if (o < 32)      { src = qw + (size_t)o * Cc; scale = 1.44269504088896f; }
    else if (o < 64) { src = kw + (size_t)(o - 32) * Cc; }
    else             { src = vw + (size_t)(o - 64) * Cc; }
    const float* s8 = src + 32 * kc + 8 * qd;
    uint4 u;
    u.x = pk2(s8[0] * scale, s8[1] * scale);
    u.y = pk2(s8[2] * scale, s8[3] * scale);
    u.z = pk2(s8[4] * scale, s8[5] * scale);
    u.w = pk2(s8[6] * scale, s8[7] * scale);
    *(uint4*)(wpk + (size_t)g * 8) = u;
}

// ---------------------------------------------------------------------------
// proj: qkv = W x, bf16 MFMA.  grid (Nn/32, 1, B) = 512 blocks, 256 thr.
// Outputs: q_t/k_t [b][n][32d] (unchanged); V now written FRAGMENT-MAJOR:
//   v_pk short idx(b,jt,c,s) = (((b*64+jt)*32 + (c>>4)*2 + (s>>5))*64
//                               + ((s>>3)&3)*16 + (c&15))*8 + (s&7)
// where s = kappa slot(j) = 4*(j&15) + ((j>>4)&3) within the 64-group jt.
// Same VALUES as before, permuted addresses only: attn's per-wave V-frag
// read becomes base + lane*8 = 1024B contiguous.
// ---------------------------------------------------------------------------
__global__ __launch_bounds__(256) void proj(
    const float* __restrict__ x, const short* __restrict__ wpk,
    short* __restrict__ q_t, short* __restrict__ k_t, short* __restrict__ v_b) {
    __shared__ alignas(16) short xs[32 * XST];   // 16.9 KB
    const int b = blockIdx.z;
    const int n0 = blockIdx.x * 32;
    const int tid = threadIdx.x;
    const int w = tid >> 6;
    const int lane = tid & 63, qd = lane >> 4, m = lane & 15;

    // ---- stage x^T tile (bf16): thread t covers n = t&31, c-range 32*(t>>5) ----
    {
        const int n = tid & 31, cg = tid >> 5;
        const float* xp = x + ((size_t)b * Cc + 32 * cg) * Nn + n0 + n;
        float xv[32];
#pragma unroll
        for (int i = 0; i < 32; ++i) xv[i] = xp[(size_t)i * Nn];
        short* row = xs + n * XST + 32 * cg;
#pragma unroll
        for (int u4 = 0; u4 < 4; ++u4)
            *(uint4*)(row + 8 * u4) = make_uint4(
                pk2(xv[8*u4+0], xv[8*u4+1]), pk2(xv[8*u4+2], xv[8*u4+3]),
                pk2(xv[8*u4+4], xv[8*u4+5]), pk2(xv[8*u4+6], xv[8*u4+7]));
    }
    __syncthreads();

    // ---- GEMM: wave w owns o-tiles ot = 4i + w ----
    const int fslot = m * 4 + qd;
    f32x4 acc[5][2];
#pragma unroll
    for (int i = 0; i < 5; ++i)
#pragma unroll
        for (int nt = 0; nt < 2; ++nt) acc[i][nt] = (f32x4){0.f, 0.f, 0.f, 0.f};

    bf16x8 afc[5], afn[5];
#pragma unroll
    for (int i = 0; i < 5; ++i)
        afc[i] = *(const bf16x8*)(wpk + ((size_t)((4*i + w) * 8 + 0) * 64 + fslot) * 8);

    for (int kc = 0; kc < 8; ++kc) {
        if (kc < 7) {
#pragma unroll
            for (int i = 0; i < 5; ++i)
                afn[i] = *(const bf16x8*)(
                    wpk + ((size_t)((4*i + w) * 8 + kc + 1) * 64 + fslot) * 8);
        }
        const bf16x8 b0 = *(const bf16x8*)&xs[(     m) * XST + 32 * kc + 8 * qd];
        const bf16x8 b1 = *(const bf16x8*)&xs[(16 + m) * XST + 32 * kc + 8 * qd];
#pragma unroll
        for (int i = 0; i < 5; ++i)
            acc[i][0] = __builtin_amdgcn_mfma_f32_16x16x32_bf16(afc[i], b0, acc[i][0], 0, 0, 0);
#pragma unroll
        for (int i = 0; i < 5; ++i)
            acc[i][1] = __builtin_amdgcn_mfma_f32_16x16x32_bf16(afc[i], b1, acc[i][1], 0, 0, 0);
#pragma unroll
        for (int i = 0; i < 5; ++i) afc[i] = afn[i];
    }

    // ---- epilogue: C row = 16*ot + 4*qd + rr, col n = n0 + 16*nt + m ----
#pragma unroll
    for (int i = 0; i < 5; ++i) {
        const int ot = 4 * i + w;
        if (ot < 4) {
            short* dst = (ot < 2 ? q_t : k_t) + (size_t)b * Nn * Dd;
            const int dbase = (ot & 1) * 16 + 4 * qd;
#pragma unroll
            for (int nt = 0; nt < 2; ++nt) {
                const f32x4 a = acc[i][nt];
                *(uint2*)(dst + (size_t)(n0 + 16 * nt + m) * Dd + dbase) =
                    make_uint2(pk2(a[0], a[1]), pk2(a[2], a[3]));
            }
        } else {
            // V fragment-major write: c = 16*(ot-4) + 4*qd + rr,
            // u32 covers slots s0 = 4m+2*b5, s0+1  (nt = 0,1).
            const int ct = ot - 4;
            const int jt = n0 >> 6;
            const int b5 = (n0 >> 5) & 1;
            const size_t vbase =
                (((size_t)(b * 64 + jt) * 32 + ct * 2 + (m >> 3)) * 64
                 + ((m >> 1) & 3) * 16 + 4 * qd) * 8 + 4 * (m & 1) + 2 * b5;
#pragma unroll
            for (int rr = 0; rr < 4; ++rr) {
                const unsigned pv = pk2(acc[i][0][rr], acc[i][1][rr]);
                *(unsigned*)(v_b + vbase + rr * 8) = pv;
            }
        }
    }
}

// ---------------------------------------------------------------------------
// attn: flash attention, 32 q-rows x ALL 256 channels per block.
// grid 512 blocks x 256 thr (4 waves) -> 2 independent blocks/CU (overlap).
//   XCD decode: xcd = fb&7, b = xcd>>1 (one batch per XCD pair -> V+K+Q
//   L2-resident, ~2.6 MB < 4 MB), i0 = (((xcd&1)<<6)|(fb>>3))*32 (bijective).
//   QK: wave (rt=w&1, kh=w>>1): rows 16rt.., keys 32kh.. (2 MFMA, 8 exp2).
//   P -> LDS p_s[32][72], kappa slot u32 @ [row][4m+2kh].
//   PV: wave w owns channels 64w..; V frags DIRECT from fragment-major v_pk:
//   each instr reads base+lane*8 = 1024B contiguous (8 lines, coalesced).
//   K LDS double-buffered, prefetch after B2 (hides under PV). Q direct
//   from global. setprio(1) around PV MFMA cluster. LDS 17.4 KB.
// ---------------------------------------------------------------------------
__global__ __launch_bounds__(256) void attn(
    const float* __restrict__ x, const short* __restrict__ q_t,
    const short* __restrict__ k_t, const short* __restrict__ v_b,
    const float* __restrict__ gamma, float* __restrict__ out) {
    __shared__ alignas(16) char pool[17408];
    short* p_s = (short*)(pool + 8192);     // [32][72] bf16 (loop)
    float* l_s = (float*)(pool + 16896);    // [2][32] f32
    float* o_t = (float*)pool;              // [32][132] f32 epilogue overlay

    const int fb  = blockIdx.x;             // 0..511
    const int xcd = fb & 7;
    const int b   = xcd >> 1;
    const int i0  = (((xcd & 1) << 6) | (fb >> 3)) << 5;
    const int tid = threadIdx.x;
    const int w = tid >> 6, lane = tid & 63;
    const int qd = lane >> 4, m = lane & 15;
    const int rt = w & 1, kh = w >> 1;

    const short* ktb = k_t + (size_t)b * Nn * Dd;

    // loop-invariant Q fragment straight from global (rows i0+16rt+m)
    const bf16x8 af = *(const bf16x8*)(
        q_t + ((size_t)b * Nn + i0 + 16 * rt + m) * Dd + 8 * qd);

    // stage first K tile (4 KB = 256 thr x 16 B)
    load_lds16(ktb + tid * 8, pool + tid * 16);

    f32x4 oacc[2][4];
#pragma unroll
    for (int mt = 0; mt < 2; ++mt)
#pragma unroll
        for (int ct = 0; ct < 4; ++ct) oacc[mt][ct] = (f32x4){0.f, 0.f, 0.f, 0.f};
    float l_i[4] = {0.f, 0.f, 0.f, 0.f};

    __syncthreads();   // K[0] arrived (vmcnt drain at barrier)

    int cur = 0;
    for (int jt = 0; jt < Nn / 64; ++jt) {
        const short* k_s = (const short*)(pool + 4096 * cur);
        if (jt) __syncthreads();   // B1: K[cur] arrived; prior p_s reads done

        // V fragments, fragment-major: 8 x 1024B-contiguous wave loads
        bf16x8 vf[4][2];
#pragma unroll
        for (int ct = 0; ct < 4; ++ct)
#pragma unroll
            for (int kc = 0; kc < 2; ++kc)
                vf[ct][kc] = *(const bf16x8*)(
                    v_b + ((((size_t)(b * 64 + jt)) * 32 +
                            (4 * w + ct) * 2 + kc) * 64 + lane) * 8);

        // ---- S' = (log2e*Q) K^T : 16 rows x 32 keys per wave ----
        const bf16x8 bk0 = *(const bf16x8*)(k_s + (16 * (2 * kh + 0) + m) * Dd + 8 * qd);
        const bf16x8 bk1 = *(const bf16x8*)(k_s + (16 * (2 * kh + 1) + m) * Dd + 8 * qd);
        const f32x4 s0 = __builtin_amdgcn_mfma_f32_16x16x32_bf16(
            af, bk0, (f32x4){0.f, 0.f, 0.f, 0.f}, 0, 0, 0);
        const f32x4 s1 = __builtin_amdgcn_mfma_f32_16x16x32_bf16(
            af, bk1, (f32x4){0.f, 0.f, 0.f, 0.f}, 0, 0, 0);

        // ---- P = exp2(S'), l partials, packed kappa P write ----
#pragma unroll
        for (int rr = 0; rr < 4; ++rr) {
            const float p0 = fexp2(s0[rr]);
            const float p1 = fexp2(s1[rr]);
            l_i[rr] += p0 + p1;
            *(unsigned*)&p_s[(16 * rt + 4 * qd + rr) * 72 + 4 * m + 2 * kh] =
                pk2(p0, p1);
        }
        __syncthreads();   // B2: p_s visible; vf drained

        // K prefetch for next tile — stays in flight through PV
        if (jt + 1 < Nn / 64)
            load_lds16(ktb + (size_t)(jt + 1) * 2048 + tid * 8,
                       pool + 4096 * (cur ^ 1) + tid * 16);

        // ---- PV: O[32 x 64 ch] += P V^T ----
        __builtin_amdgcn_s_setprio(1);
#pragma unroll
        for (int kc = 0; kc < 2; ++kc) {
            bf16x8 pa[2];
#pragma unroll
            for (int mt = 0; mt < 2; ++mt)
                pa[mt] = *(const bf16x8*)&p_s[(16 * mt + m) * 72 + 32 * kc + 8 * qd];
#pragma unroll
            for (int ct = 0; ct < 4; ++ct)
#pragma unroll
                for (int mt = 0; mt < 2; ++mt)
                    oacc[mt][ct] = __builtin_amdgcn_mfma_f32_16x16x32_bf16(
                        pa[mt], vf[ct][kc], oacc[mt][ct], 0, 0, 0);
        }
        __builtin_amdgcn_s_setprio(0);
        cur ^= 1;
    }

    // final l reduction: per kh-half row sums, combined in epilogue
#pragma unroll
    for (int rr = 0; rr < 4; ++rr) l_i[rr] = rowsum16(l_i[rr]);
    if (m == 0)
        *(f32x4*)&l_s[kh * 32 + 16 * rt + 4 * qd] =
            (f32x4){l_i[0], l_i[1], l_i[2], l_i[3]};
    __syncthreads();   // l published; loop LDS dead -> o_t overlay safe

    // ---- epilogue: transpose O via LDS overlay, out = gamma*O/l + x ----
    const float g = gamma[0];
    const int i = tid & 31, cg8 = tid >> 5;   // row, col-group
    const float linv = 1.0f / (l_s[i] + l_s[32 + i]);
#pragma unroll
    for (int ps = 0; ps < 2; ++ps) {
        if (ps) __syncthreads();
#pragma unroll
        for (int ctp = 0; ctp < 2; ++ctp)
#pragma unroll
            for (int mt = 0; mt < 2; ++mt)
#pragma unroll
                for (int rr = 0; rr < 4; ++rr)
                    o_t[(16 * mt + 4 * qd + rr) * 132 + 32 * w + 16 * ctp + m] =
                        oacc[mt][2 * ps + ctp][rr];
        __syncthreads();
#pragma unroll
        for (int u = 0; u < 4; ++u) {
            const f32x4 v4 = *(const f32x4*)&o_t[i * 132 + 16 * cg8 + 4 * u];
#pragma unroll
            for (int e = 0; e < 4; ++e) {
                const int col = 16 * cg8 + 4 * u + e;
                const int c = 64 * (col >> 5) + 32 * ps + (col & 31);
                const size_t gidx = ((size_t)b * Cc + c) * Nn + i0 + i;
                out[gidx] = g * v4[e] * linv + x[gidx];
            }
        }
    }
}

// ---------------------------------------------------------------------------
extern "C" void kernel_launch(void* const* d_in, const int* in_sizes, int n_in,
                              void* d_out, int out_size, void* d_ws, size_t ws_size,
                              hipStream_t stream) {
    const float* x     = (const float*)d_in[0];
    const float* qw    = (const float*)d_in[1];
    const float* kw    = (const float*)d_in[2];
    const float* vw    = (const float*)d_in[3];
    const float* gamma = (const float*)d_in[4];
    float* out = (float*)d_out;

    short* q_t = (short*)d_ws;                       // [b][n][32] bf16, 1 MB
    short* k_t = q_t + (size_t)Bb * Nn * Dd;         // [b][n][32] bf16, 1 MB
    short* v_b = k_t + (size_t)Bb * Nn * Dd;         // fragment-major V, 8.4 MB
    short* wpk = v_b + (size_t)Bb * Cc * Nn;         // 160 KB packed W

    pack_w<<<dim3(40), 256, 0, stream>>>(qw, kw, vw, wpk);
    proj<<<dim3(Nn / 32, 1, Bb), 256, 0, stream>>>(x, wpk, q_t, k_t, v_b);
    attn<<<dim3(512), 256, 0, stream>>>(x, q_t, k_t, v_b, gamma, out);
}

// Round 5
// 142.535 us; speedup vs baseline: 1.2288x; 1.0528x over previous
//
#include <hip/hip_runtime.h>
#include <math.h>

#define Bb 4
#define Cc 256
#define Nn 4096
#define Dd 32
#define XST 264   // proj x-tile LDS row stride (shorts)

typedef __attribute__((ext_vector_type(8))) short bf16x8;
typedef __attribute__((ext_vector_type(4))) float f32x4;

__device__ __forceinline__ unsigned short f2bf(float x) {
    union { float f; unsigned u; } c; c.f = x;
    unsigned r = c.u + 0x7fffu + ((c.u >> 16) & 1u);   // RNE
    return (unsigned short)(r >> 16);
}
__device__ __forceinline__ unsigned pk2(float a, float b) {
    return (unsigned)f2bf(a) | ((unsigned)f2bf(b) << 16);
}
__device__ __forceinline__ float fexp2(float x) {
#if __has_builtin(__builtin_amdgcn_exp2f)
    return __builtin_amdgcn_exp2f(x);
#else
    return __exp2f(x);
#endif
}
// DPP sum over the 16-lane row (used ONCE, after the jt loop)
template <int CTRL>
__device__ __forceinline__ float dppf(float v) {
    int iv = __builtin_bit_cast(int, v);
    return __builtin_bit_cast(float,
        __builtin_amdgcn_update_dpp(iv, iv, CTRL, 0xF, 0xF, false));
}
__device__ __forceinline__ float rowsum16(float v) {
    v += dppf<0xB1>(v);    // quad xor1
    v += dppf<0x4E>(v);    // quad xor2
    v += dppf<0x141>(v);   // row_half_mirror
    v += dppf<0x140>(v);   // row_mirror
    return v;
}

// ---------------------------------------------------------------------------
// pack_w: W (q|k|v concat, 320 rows x 256) -> bf16 MFMA-fragment-major layout.
// Q rows pre-scaled by log2(e). grid 40 x 256.   (UNCHANGED)
// ---------------------------------------------------------------------------
__global__ __launch_bounds__(256) void pack_w(
    const float* __restrict__ qw, const float* __restrict__ kw,
    const float* __restrict__ vw, short* __restrict__ wpk) {
    const int g = blockIdx.x * 256 + threadIdx.x;   // 10240 frags
    const int qd = g & 3, m = (g >> 2) & 15, kc = (g >> 6) & 7, ot = g >> 9;
    const int o = 16 * ot + m;
    const float* src;
    float scale = 1.0f;
    if (o < 32)      { src = qw + (size_t)o * Cc; scale = 1.44269504088896f; }
    else if (o < 64) { src = kw + (size_t)(o - 32) * Cc; }
    else             { src = vw + (size_t)(o - 64) * Cc; }
    const float* s8 = src + 32 * kc + 8 * qd;
    uint4 u;
    u.x = pk2(s8[0] * scale, s8[1] * scale);
    u.y = pk2(s8[2] * scale, s8[3] * scale);
    u.z = pk2(s8[4] * scale, s8[5] * scale);
    u.w = pk2(s8[6] * scale, s8[7] * scale);
    *(uint4*)(wpk + (size_t)g * 8) = u;
}

// ---------------------------------------------------------------------------
// proj: qkv = W x, bf16 MFMA.  grid (Nn/32, 1, B) = 512 blocks, 256 thr.
// Outputs: q_t/k_t [b][n][32d]; V fragment-major (attn B-frag = base+lane*8).
// (UNCHANGED from round 3 — verified passing)
// ---------------------------------------------------------------------------
__global__ __launch_bounds__(256) void proj(
    const float* __restrict__ x, const short* __restrict__ wpk,
    short* __restrict__ q_t, short* __restrict__ k_t, short* __restrict__ v_b) {
    __shared__ alignas(16) short xs[32 * XST];   // 16.9 KB
    const int b = blockIdx.z;
    const int n0 = blockIdx.x * 32;
    const int tid = threadIdx.x;
    const int w = tid >> 6;
    const int lane = tid & 63, qd = lane >> 4, m = lane & 15;

    // ---- stage x^T tile (bf16): thread t covers n = t&31, c-range 32*(t>>5) ----
    {
        const int n = tid & 31, cg = tid >> 5;
        const float* xp = x + ((size_t)b * Cc + 32 * cg) * Nn + n0 + n;
        float xv[32];
#pragma unroll
        for (int i = 0; i < 32; ++i) xv[i] = xp[(size_t)i * Nn];
        short* row = xs + n * XST + 32 * cg;
#pragma unroll
        for (int u4 = 0; u4 < 4; ++u4)
            *(uint4*)(row + 8 * u4) = make_uint4(
                pk2(xv[8*u4+0], xv[8*u4+1]), pk2(xv[8*u4+2], xv[8*u4+3]),
                pk2(xv[8*u4+4], xv[8*u4+5]), pk2(xv[8*u4+6], xv[8*u4+7]));
    }
    __syncthreads();

    // ---- GEMM: wave w owns o-tiles ot = 4i + w ----
    const int fslot = m * 4 + qd;
    f32x4 acc[5][2];
#pragma unroll
    for (int i = 0; i < 5; ++i)
#pragma unroll
        for (int nt = 0; nt < 2; ++nt) acc[i][nt] = (f32x4){0.f, 0.f, 0.f, 0.f};

    bf16x8 afc[5], afn[5];
#pragma unroll
    for (int i = 0; i < 5; ++i)
        afc[i] = *(const bf16x8*)(wpk + ((size_t)((4*i + w) * 8 + 0) * 64 + fslot) * 8);

    for (int kc = 0; kc < 8; ++kc) {
        if (kc < 7) {
#pragma unroll
            for (int i = 0; i < 5; ++i)
                afn[i] = *(const bf16x8*)(
                    wpk + ((size_t)((4*i + w) * 8 + kc + 1) * 64 + fslot) * 8);
        }
        const bf16x8 b0 = *(const bf16x8*)&xs[(     m) * XST + 32 * kc + 8 * qd];
        const bf16x8 b1 = *(const bf16x8*)&xs[(16 + m) * XST + 32 * kc + 8 * qd];
#pragma unroll
        for (int i = 0; i < 5; ++i)
            acc[i][0] = __builtin_amdgcn_mfma_f32_16x16x32_bf16(afc[i], b0, acc[i][0], 0, 0, 0);
#pragma unroll
        for (int i = 0; i < 5; ++i)
            acc[i][1] = __builtin_amdgcn_mfma_f32_16x16x32_bf16(afc[i], b1, acc[i][1], 0, 0, 0);
#pragma unroll
        for (int i = 0; i < 5; ++i) afc[i] = afn[i];
    }

    // ---- epilogue: C row = 16*ot + 4*qd + rr, col n = n0 + 16*nt + m ----
#pragma unroll
    for (int i = 0; i < 5; ++i) {
        const int ot = 4 * i + w;
        if (ot < 4) {
            short* dst = (ot < 2 ? q_t : k_t) + (size_t)b * Nn * Dd;
            const int dbase = (ot & 1) * 16 + 4 * qd;
#pragma unroll
            for (int nt = 0; nt < 2; ++nt) {
                const f32x4 a = acc[i][nt];
                *(uint2*)(dst + (size_t)(n0 + 16 * nt + m) * Dd + dbase) =
                    make_uint2(pk2(a[0], a[1]), pk2(a[2], a[3]));
            }
        } else {
            // V fragment-major write: c = 16*(ot-4) + 4*qd + rr,
            // u32 covers slots s0 = 4m+2*b5, s0+1  (nt = 0,1).
            const int ct = ot - 4;
            const int jt = n0 >> 6;
            const int b5 = (n0 >> 5) & 1;
            const size_t vbase =
                (((size_t)(b * 64 + jt) * 32 + ct * 2 + (m >> 3)) * 64
                 + ((m >> 1) & 3) * 16 + 4 * qd) * 8 + 4 * (m & 1) + 2 * b5;
#pragma unroll
            for (int rr = 0; rr < 4; ++rr) {
                const unsigned pv = pk2(acc[i][0][rr], acc[i][1][rr]);
                *(unsigned*)(v_b + vbase + rr * 8) = pv;
            }
        }
    }
}

// ---------------------------------------------------------------------------
// attn: flash attention, 32 q-rows x 256 ch per block, 512 blocks x 256 thr.
// Round-4 surgery (math identical to round 3, data paths changed):
//   - K frags DIRECT from global (k_t rows are frag-contiguous 1024B reads);
//     K LDS staging deleted.
//   - p_s double-buffered (buf per tile parity) -> ONE barrier per tile
//     (WAR on a buffer is separated by the next tile's barrier).
//   - Manual 2-tile unroll, ping-pong register sets (no copies): K frags
//     prefetched 2 tiles ahead, V frags 1 tile ahead, issued right after
//     the barrier so they complete under PV+QK (~400 cyc slack).
//   - p_s PV read is the optimal 8-phase b128 pattern (conflict-free).
// LDS 17.4 KB -> 2 blocks/CU co-resident for barrier overlap.
// ---------------------------------------------------------------------------
__global__ __launch_bounds__(256, 2) void attn(
    const float* __restrict__ x, const short* __restrict__ q_t,
    const short* __restrict__ k_t, const short* __restrict__ v_b,
    const float* __restrict__ gamma, float* __restrict__ out) {
    __shared__ alignas(16) char pool[17408];
    // loop: p_s buf0 @0 (4608B), buf1 @4608 ; l_s @16896 ; epilogue o_t @0
    float* l_s = (float*)(pool + 16896);    // [2][32] f32
    float* o_t = (float*)pool;              // [32][132] f32 epilogue overlay

    const int fb  = blockIdx.x;             // 0..511
    const int xcd = fb & 7;
    const int b   = xcd >> 1;
    const int i0  = (((xcd & 1) << 6) | (fb >> 3)) << 5;
    const int tid = threadIdx.x;
    const int w = tid >> 6, lane = tid & 63;
    const int qd = lane >> 4, m = lane & 15;
    const int rt = w & 1, kh = w >> 1;

    // loop-invariant Q fragment (rows i0+16rt+m)
    const bf16x8 af = *(const bf16x8*)(
        q_t + ((size_t)b * Nn + i0 + 16 * rt + m) * Dd + 8 * qd);

    // K frag base: tile jt at kf + jt*2048 (+512 for second 16-key half)
    const short* kf = k_t + (size_t)b * Nn * Dd + (32 * kh + m) * Dd + 8 * qd;
    // V frag base: tile jt at vw + jt*16384 + (2ct+kc)*512
    const short* vw = v_b + (size_t)b * (64 * 32 * 64 * 8) + w * 4096 + lane * 8;

    // prologue: K frags for tiles 0,1; V frags for tile 0
    bf16x8 bkA0 = *(const bf16x8*)(kf);
    bf16x8 bkA1 = *(const bf16x8*)(kf + 512);
    bf16x8 bkB0 = *(const bf16x8*)(kf + 2048);
    bf16x8 bkB1 = *(const bf16x8*)(kf + 2560);
    bf16x8 vfA[4][2], vfB[4][2];
#pragma unroll
    for (int ct = 0; ct < 4; ++ct)
#pragma unroll
        for (int kc = 0; kc < 2; ++kc)
            vfA[ct][kc] = *(const bf16x8*)(vw + (2 * ct + kc) * 512);

    f32x4 oacc[2][4];
#pragma unroll
    for (int mt = 0; mt < 2; ++mt)
#pragma unroll
        for (int ct = 0; ct < 4; ++ct) oacc[mt][ct] = (f32x4){0.f, 0.f, 0.f, 0.f};
    float l_i[4] = {0.f, 0.f, 0.f, 0.f};

    const short* kpre = kf + 4096;    // K for jt+2 (A) / jt+3 (@+2048)
    const short* vpre = vw + 16384;   // V for jt+1 (A) / jt+2 (@+16384)

    for (int j2 = 0; j2 < 32; ++j2) {
        const bool pre = (j2 < 31);
        // ================= phase A: tile jt = 2*j2, p_s buf 0 =================
        {
            short* ps = (short*)pool;
            const f32x4 s0 = __builtin_amdgcn_mfma_f32_16x16x32_bf16(
                af, bkA0, (f32x4){0.f, 0.f, 0.f, 0.f}, 0, 0, 0);
            const f32x4 s1 = __builtin_amdgcn_mfma_f32_16x16x32_bf16(
                af, bkA1, (f32x4){0.f, 0.f, 0.f, 0.f}, 0, 0, 0);
            if (pre) {   // K prefetch, 2 tiles ahead
                bkA0 = *(const bf16x8*)(kpre);
                bkA1 = *(const bf16x8*)(kpre + 512);
            }
#pragma unroll
            for (int rr = 0; rr < 4; ++rr) {
                const float p0 = fexp2(s0[rr]);
                const float p1 = fexp2(s1[rr]);
                l_i[rr] += p0 + p1;
                *(unsigned*)&ps[(16 * rt + 4 * qd + rr) * 72 + 4 * m + 2 * kh] =
                    pk2(p0, p1);
            }
            __syncthreads();   // p_s buf0 visible
            // V prefetch for tile jt+1 (always valid: jt+1 <= 63)
#pragma unroll
            for (int ct = 0; ct < 4; ++ct)
#pragma unroll
                for (int kc = 0; kc < 2; ++kc)
                    vfB[ct][kc] = *(const bf16x8*)(vpre + (2 * ct + kc) * 512);
            __builtin_amdgcn_s_setprio(1);
#pragma unroll
            for (int kc = 0; kc < 2; ++kc) {
                bf16x8 pa[2];
#pragma unroll
                for (int mt = 0; mt < 2; ++mt)
                    pa[mt] = *(const bf16x8*)&ps[(16 * mt + m) * 72 + 32 * kc + 8 * qd];
#pragma unroll
                for (int ct = 0; ct < 4; ++ct)
#pragma unroll
                    for (int mt = 0; mt < 2; ++mt)
                        oacc[mt][ct] = __builtin_amdgcn_mfma_f32_16x16x32_bf16(
                            pa[mt], vfA[ct][kc], oacc[mt][ct], 0, 0, 0);
            }
            __builtin_amdgcn_s_setprio(0);
        }
        // ================= phase B: tile 2*j2+1, p_s buf 1 =================
        {
            short* ps = (short*)(pool + 4608);
            const f32x4 s0 = __builtin_amdgcn_mfma_f32_16x16x32_bf16(
                af, bkB0, (f32x4){0.f, 0.f, 0.f, 0.f}, 0, 0, 0);
            const f32x4 s1 = __builtin_amdgcn_mfma_f32_16x16x32_bf16(
                af, bkB1, (f32x4){0.f, 0.f, 0.f, 0.f}, 0, 0, 0);
            if (pre) {   // K prefetch, 2 tiles ahead
                bkB0 = *(const bf16x8*)(kpre + 2048);
                bkB1 = *(const bf16x8*)(kpre + 2560);
            }
#pragma unroll
            for (int rr = 0; rr < 4; ++rr) {
                const float p0 = fexp2(s0[rr]);
                const float p1 = fexp2(s1[rr]);
                l_i[rr] += p0 + p1;
                *(unsigned*)&ps[(16 * rt + 4 * qd + rr) * 72 + 4 * m + 2 * kh] =
                    pk2(p0, p1);
            }
            __syncthreads();   // p_s buf1 visible
            if (pre) {   // V prefetch for tile jt+2
#pragma unroll
                for (int ct = 0; ct < 4; ++ct)
#pragma unroll
                    for (int kc = 0; kc < 2; ++kc)
                        vfA[ct][kc] = *(const bf16x8*)(vpre + 16384 + (2 * ct + kc) * 512);
            }
            __builtin_amdgcn_s_setprio(1);
#pragma unroll
            for (int kc = 0; kc < 2; ++kc) {
                bf16x8 pa[2];
#pragma unroll
                for (int mt = 0; mt < 2; ++mt)
                    pa[mt] = *(const bf16x8*)&ps[(16 * mt + m) * 72 + 32 * kc + 8 * qd];
#pragma unroll
                for (int ct = 0; ct < 4; ++ct)
#pragma unroll
                    for (int mt = 0; mt < 2; ++mt)
                        oacc[mt][ct] = __builtin_amdgcn_mfma_f32_16x16x32_bf16(
                            pa[mt], vfB[ct][kc], oacc[mt][ct], 0, 0, 0);
            }
            __builtin_amdgcn_s_setprio(0);
        }
        kpre += 4096;
        vpre += 32768;
    }

    // final l reduction: per kh-half row sums, combined in epilogue
#pragma unroll
    for (int rr = 0; rr < 4; ++rr) l_i[rr] = rowsum16(l_i[rr]);
    if (m == 0)
        *(f32x4*)&l_s[kh * 32 + 16 * rt + 4 * qd] =
            (f32x4){l_i[0], l_i[1], l_i[2], l_i[3]};
    __syncthreads();   // l published; loop LDS dead -> o_t overlay safe

    // ---- epilogue: transpose O via LDS overlay, out = gamma*O/l + x ----
    const float g = gamma[0];
    const int i = tid & 31, cg8 = tid >> 5;   // row, col-group
    const float linv = 1.0f / (l_s[i] + l_s[32 + i]);
#pragma unroll
    for (int ps = 0; ps < 2; ++ps) {
        if (ps) __syncthreads();
#pragma unroll
        for (int ctp = 0; ctp < 2; ++ctp)
#pragma unroll
            for (int mt = 0; mt < 2; ++mt)
#pragma unroll
                for (int rr = 0; rr < 4; ++rr)
                    o_t[(16 * mt + 4 * qd + rr) * 132 + 32 * w + 16 * ctp + m] =
                        oacc[mt][2 * ps + ctp][rr];
        __syncthreads();
#pragma unroll
        for (int u = 0; u < 4; ++u) {
            const f32x4 v4 = *(const f32x4*)&o_t[i * 132 + 16 * cg8 + 4 * u];
#pragma unroll
            for (int e = 0; e < 4; ++e) {
                const int col = 16 * cg8 + 4 * u + e;
                const int c = 64 * (col >> 5) + 32 * ps + (col & 31);
                const size_t gidx = ((size_t)b * Cc + c) * Nn + i0 + i;
                out[gidx] = g * v4[e] * linv + x[gidx];
            }
        }
    }
}

// ---------------------------------------------------------------------------
extern "C" void kernel_launch(void* const* d_in, const int* in_sizes, int n_in,
                              void* d_out, int out_size, void* d_ws, size_t ws_size,
                              hipStream_t stream) {
    const float* x     = (const float*)d_in[0];
    const float* qw    = (const float*)d_in[1];
    const float* kw    = (const float*)d_in[2];
    const float* vw    = (const float*)d_in[3];
    const float* gamma = (const float*)d_in[4];
    float* out = (float*)d_out;

    short* q_t = (short*)d_ws;                       // [b][n][32] bf16, 1 MB
    short* k_t = q_t + (size_t)Bb * Nn * Dd;         // [b][n][32] bf16, 1 MB
    short* v_b = k_t + (size_t)Bb * Nn * Dd;         // fragment-major V, 8.4 MB
    short* wpk = v_b + (size_t)Bb * Cc * Nn;         // 160 KB packed W

    pack_w<<<dim3(40), 256, 0, stream>>>(qw, kw, vw, wpk);
    proj<<<dim3(Nn / 32, 1, Bb), 256, 0, stream>>>(x, wpk, q_t, k_t, v_b);
    attn<<<dim3(512), 256, 0, stream>>>(x, q_t, k_t, v_b, gamma, out);
}